// Round 6
// baseline (67.702 us; speedup 1.0000x reference)
//
#include <hip/hip_runtime.h>

#define N_PIX 4096
#define N_CH 256
#define KSEL 16
#define CCAP 128

__device__ __forceinline__ unsigned f2key(float f) {
  unsigned u = __float_as_uint(f);
  return u ^ ((unsigned)((int)u >> 31) | 0x80000000u);
}
__device__ __forceinline__ float key2f(unsigned k) {
  unsigned u = (k & 0x80000000u) ? (k ^ 0x80000000u) : ~k;
  return __uint_as_float(u);
}
__device__ __forceinline__ unsigned umax2(unsigned a, unsigned b) { return a > b ? a : b; }

// feat [B, C, N] -> feat_t [B, N, C], 32x32 LDS tile transpose
__global__ void transpose_feat_kernel(const float* __restrict__ feat,
                                      float* __restrict__ feat_t) {
  __shared__ float tile[32][33];
  const int b = blockIdx.z;
  const int n0 = blockIdx.x * 32;
  const int c0 = blockIdx.y * 32;
  const int tx = threadIdx.x, ty = threadIdx.y;
  const float* src = feat + (size_t)b * N_CH * N_PIX;
  float* dst = feat_t + (size_t)b * N_PIX * N_CH;
#pragma unroll
  for (int j = 0; j < 32; j += 8)
    tile[ty + j][tx] = src[(size_t)(c0 + ty + j) * N_PIX + n0 + tx];
  __syncthreads();
#pragma unroll
  for (int j = 0; j < 32; j += 8)
    dst[(size_t)(n0 + ty + j) * N_CH + c0 + tx] = tile[tx][ty + j];
}

// Block = 4 waves, one row per wave. TWO-PASS selection (row never held in
// registers -> ~50-90 VGPR, no spill):
//   pass 1: stream row, per-lane max only.
//   T1 = exact 16th-largest lane-max (32-step branchless ballot-radix).
//        Superset guarantee: >=16 elements >= T1, and every row-top-16
//        element is >= T1 (16 lanes each contain an element >= T1).
//   pass 2: re-stream row FROM L2, ballot-rank compact candidates >= T1
//        (E[count] ~ 18-25, cap 128) into per-wave LDS slab.
//   stage 2: exact tie-correct top-16 over <=128 candidates (2 per lane).
// Softmax uses the true row max (numerically safe); normalization deferred
// to the gather epilogue. One barrier/block (full-line float4 output).
template <bool FT>
__global__ __launch_bounds__(256, 4) void topk_2pass_kernel(
    const float* __restrict__ aff, const float* __restrict__ feat,
    float* __restrict__ out) {
  __shared__ unsigned s_ck[4][CCAP];
  __shared__ unsigned s_cj[4][CCAP];
  __shared__ uint2 s_wj[4][KSEL];   // (exp(v - vmax) bits, index)
  __shared__ float s_out[4][N_CH];

  const int tid = threadIdx.x;
  const int lane = tid & 63;
  const int w = tid >> 6;
  // chunked bijective XCD swizzle (2048 = 8 * 256): consecutive rg share an
  // XCD -> the 4 blocks writing each 64B output line write-combine in one L2.
  const int bid = blockIdx.x;
  const int rg = (bid & 7) * 256 + (bid >> 3);
  const int b = rg >> 10;
  const int i0 = (rg & 1023) * 4;
  const int row = rg * 4 + w;
  const unsigned long long lt = (1ull << lane) - 1ull;

  const float4* arow = (const float4*)(aff + (size_t)row * N_PIX);

  // ---- pass 1: stream row, per-lane max of sortable keys ----
  unsigned m = 0;
#pragma unroll
  for (int q = 0; q < 16; ++q) {
    float4 v = arow[q * 64 + lane];
    m = umax2(m, umax2(umax2(f2key(v.x), f2key(v.y)),
                       umax2(f2key(v.z), f2key(v.w))));
  }
  // wave max (for the softmax reference point): 6-step shfl reduce
  unsigned km = m;
#pragma unroll
  for (int off = 32; off; off >>= 1)
    km = umax2(km, (unsigned)__shfl_xor((int)km, off, 64));
  const float vmax = key2f(km);

  // ---- T1 = exact 16th-largest lane-max (branchless ballot-radix) ----
  unsigned p1 = 0, need1 = KSEL;
#pragma unroll
  for (int bit = 31; bit >= 0; --bit) {
    unsigned want = (p1 << 1) | 1u;
    unsigned cnt = (unsigned)__popcll(__ballot((m >> bit) == want));
    bool take = cnt >= need1;
    p1 = want - (take ? 0u : 1u);
    need1 = take ? need1 : need1 - cnt;
  }
  const unsigned T1 = p1;

  // compiler barrier: forbid CSE of pass-2 loads with pass-1 loads (keeping
  // 64 keys live is exactly the register blow-up we're avoiding)
  asm volatile("" ::: "memory");

  // ---- pass 2: re-stream row (L2-hot), compact candidates >= T1 ----
  unsigned base = 0;
#pragma unroll
  for (int q = 0; q < 16; ++q) {
    float4 v = arow[q * 64 + lane];
    unsigned kk[4] = {f2key(v.x), f2key(v.y), f2key(v.z), f2key(v.w)};
#pragma unroll
    for (int c = 0; c < 4; ++c) {
      bool sel = kk[c] >= T1;
      unsigned long long mk = __ballot(sel);
      if (sel) {
        unsigned pos = base + (unsigned)__popcll(mk & lt);
        if (pos < CCAP) {
          s_ck[w][pos] = kk[c];
          s_cj[w][pos] = (unsigned)(q * 256 + lane * 4 + c);
        }
      }
      base += (unsigned)__popcll(mk);
    }
  }

  if (__builtin_expect(base <= CCAP, 1)) {
    // ---- stage 2: exact top-16 among <=128 candidates (2 slots/lane) ----
    unsigned cv0 = 0, cj0 = 0xFFFFFFFFu, cv1 = 0, cj1 = 0xFFFFFFFFu;
    if (lane < (int)base) { cv0 = s_ck[w][lane]; cj0 = s_cj[w][lane]; }
    if (lane + 64 < (int)base) { cv1 = s_ck[w][lane + 64]; cj1 = s_cj[w][lane + 64]; }

    unsigned p2 = 0, need2 = KSEL;
#pragma unroll
    for (int bit = 31; bit >= 0; --bit) {
      unsigned want = (p2 << 1) | 1u;
      // padded slots (cv=0) can never match: want is always odd, 0>>bit even
      unsigned cnt = (unsigned)__popcll(__ballot((cv0 >> bit) == want)) +
                     (unsigned)__popcll(__ballot((cv1 >> bit) == want));
      bool take = cnt >= need2;
      p2 = want - (take ? 0u : 1u);
      need2 = take ? need2 : need2 - cnt;
    }
    const unsigned T2 = p2;  // exact 16th-largest value; need2 ties to take

    bool win0 = cv0 > T2, win1 = cv1 > T2;
    bool eq0 = (lane < (int)base) && (cv0 == T2);
    bool eq1 = (lane + 64 < (int)base) && (cv1 == T2);
    unsigned cntEq = (unsigned)__popcll(__ballot(eq0)) +
                     (unsigned)__popcll(__ballot(eq1));
    if (cntEq == need2) {
      win0 = win0 || eq0;
      win1 = win1 || eq1;
    } else {
      // cold: lowest-index subset of the ==T2 ties (top_k semantics)
      bool t0 = eq0, t1 = eq1;
      for (unsigned q = 0; q < need2; ++q) {
        unsigned mi0 = t0 ? cj0 : 0xFFFFFFFFu;
        unsigned mi1 = t1 ? cj1 : 0xFFFFFFFFu;
        unsigned mi = mi0 < mi1 ? mi0 : mi1;
#pragma unroll
        for (int off = 32; off; off >>= 1) {
          unsigned o = (unsigned)__shfl_xor((int)mi, off, 64);
          mi = o < mi ? o : mi;
        }
        if (t0 && cj0 == mi) { win0 = true; t0 = false; }
        else if (t1 && cj1 == mi) { win1 = true; t1 = false; }
      }
    }

    unsigned long long m0 = __ballot(win0);
    unsigned long long m1 = __ballot(win1);
    const unsigned n0w = (unsigned)__popcll(m0);
    if (win0) {
      unsigned rk = (unsigned)__popcll(m0 & lt);
      s_wj[w][rk] = make_uint2(__float_as_uint(__expf(key2f(cv0) - vmax)), cj0);
    }
    if (win1) {
      unsigned rk = n0w + (unsigned)__popcll(m1 & lt);
      s_wj[w][rk] = make_uint2(__float_as_uint(__expf(key2f(cv1) - vmax)), cj1);
    }
  } else {
    // ---- measure-zero parachute: exact bit-serial radix, streaming ----
    unsigned p2 = 0, need2 = KSEL;
    for (int bit = 31; bit >= 0; --bit) {
      unsigned want = (p2 << 1) | 1u;
      unsigned cnt = 0;
      for (int q = 0; q < 16; ++q) {
        float4 v = arow[q * 64 + lane];
        cnt += (unsigned)__popcll(__ballot((f2key(v.x) >> bit) == want));
        cnt += (unsigned)__popcll(__ballot((f2key(v.y) >> bit) == want));
        cnt += (unsigned)__popcll(__ballot((f2key(v.z) >> bit) == want));
        cnt += (unsigned)__popcll(__ballot((f2key(v.w) >> bit) == want));
      }
      bool take = cnt >= need2;
      p2 = want - (take ? 0u : 1u);
      need2 = take ? need2 : need2 - cnt;
    }
    const unsigned T2 = p2;
    unsigned rk = 0;
    for (int q = 0; q < 16; ++q) {
      float4 v = arow[q * 64 + lane];
      unsigned kk[4] = {f2key(v.x), f2key(v.y), f2key(v.z), f2key(v.w)};
      for (int c = 0; c < 4; ++c) {
        bool sel = kk[c] > T2;
        unsigned long long mk = __ballot(sel);
        if (sel) {
          unsigned pos = rk + (unsigned)__popcll(mk & lt);
          if (pos < KSEL)
            s_wj[w][pos] = make_uint2(
                __float_as_uint(__expf(key2f(kk[c]) - vmax)),
                (unsigned)(q * 256 + lane * 4 + c));
        }
        rk += (unsigned)__popcll(mk);
      }
    }
    // lowest-index ties == T2, ascending
    unsigned jprev = 0xFFFFFFFFu;  // sentinel: first iteration takes global min
    for (unsigned t = rk; t < KSEL; ++t) {
      unsigned mi = 0xFFFFFFFFu;
      for (int q = 0; q < 16; ++q) {
        float4 v = arow[q * 64 + lane];
        unsigned kk[4] = {f2key(v.x), f2key(v.y), f2key(v.z), f2key(v.w)};
        for (int c = 0; c < 4; ++c) {
          unsigned j = (unsigned)(q * 256 + lane * 4 + c);
          if (kk[c] == T2 && (jprev == 0xFFFFFFFFu || j > jprev) && j < mi) mi = j;
        }
      }
#pragma unroll
      for (int off = 32; off; off >>= 1) {
        unsigned o = (unsigned)__shfl_xor((int)mi, off, 64);
        mi = o < mi ? o : mi;
      }
      if (lane == 0)
        s_wj[w][t] = make_uint2(__float_as_uint(__expf(key2f(T2) - vmax)), mi);
      jprev = mi;
    }
  }

  // ---- epilogue: softmax denominator + weighted gather (same-wave LDS RAW) ----
  float ssum = 0.f;
#pragma unroll
  for (int k = 0; k < KSEL; ++k) ssum += __uint_as_float(s_wj[w][k].x);
  const float inv = 1.0f / ssum;

  float ax = 0.f, ay = 0.f, az = 0.f, aw = 0.f;
  if (FT) {
    const float* fb = feat + (size_t)b * N_PIX * N_CH + lane * 4;  // [B,N,C]
#pragma unroll
    for (int k = 0; k < KSEL; ++k) {
      uint2 t = s_wj[w][k];
      const float ew = __uint_as_float(t.x);
      const float4 f = *(const float4*)(fb + (size_t)t.y * N_CH);
      ax += ew * f.x; ay += ew * f.y; az += ew * f.z; aw += ew * f.w;
    }
  } else {
    const float* fb = feat + (size_t)b * N_CH * N_PIX;  // [B,C,N] fallback
    const int c0 = lane * 4;
#pragma unroll
    for (int k = 0; k < KSEL; ++k) {
      uint2 t = s_wj[w][k];
      const float ew = __uint_as_float(t.x);
      ax += ew * fb[(size_t)(c0 + 0) * N_PIX + t.y];
      ay += ew * fb[(size_t)(c0 + 1) * N_PIX + t.y];
      az += ew * fb[(size_t)(c0 + 2) * N_PIX + t.y];
      aw += ew * fb[(size_t)(c0 + 3) * N_PIX + t.y];
    }
  }
  float4 accv;
  accv.x = ax * inv; accv.y = ay * inv; accv.z = az * inv; accv.w = aw * inv;
  *(float4*)&s_out[w][lane * 4] = accv;

  __syncthreads();  // only block barrier: assemble full-line output stores

  {
    const int c = tid;
    float4 o;
    o.x = s_out[0][c]; o.y = s_out[1][c]; o.z = s_out[2][c]; o.w = s_out[3][c];
    *(float4*)(out + ((size_t)(b * N_CH + c)) * N_PIX + i0) = o;
  }
}

extern "C" void kernel_launch(void* const* d_in, const int* in_sizes, int n_in,
                              void* d_out, int out_size, void* d_ws, size_t ws_size,
                              hipStream_t stream) {
  const float* aff = (const float*)d_in[0];
  const float* feat = (const float*)d_in[1];
  float* out = (float*)d_out;
  const size_t feat_t_bytes = (size_t)2 * N_PIX * N_CH * sizeof(float);
  if (ws_size >= feat_t_bytes) {
    float* feat_t = (float*)d_ws;
    dim3 tb(32, 8, 1);
    dim3 tg(N_PIX / 32, N_CH / 32, 2);
    transpose_feat_kernel<<<tg, tb, 0, stream>>>(feat, feat_t);
    topk_2pass_kernel<true><<<2048, 256, 0, stream>>>(aff, feat_t, out);
  } else {
    topk_2pass_kernel<false><<<2048, 256, 0, stream>>>(aff, feat, out);
  }
}